// Round 8
// baseline (592.983 us; speedup 1.0000x reference)
//
#include <hip/hip_runtime.h>
#include <cstdint>

// ---------- types ----------
typedef __bf16 bf16;
typedef __bf16 bf16x8 __attribute__((ext_vector_type(8)));
typedef float  f32x4  __attribute__((ext_vector_type(4)));

#define AS1(p) ((__attribute__((address_space(1))) void*)(p))
#define AS3(p) ((__attribute__((address_space(3))) void*)(p))

__device__ __forceinline__ void gload16(const void* g, void* l) {
  __builtin_amdgcn_global_load_lds(AS1(g), AS3(l), 16, 0, 0);
}

// ---------- problem constants ----------
constexpr int B_ = 2, S_ = 2048, E_ = 4096, H_ = 32, KVH_ = 8, D_ = 128;
constexpr int QPK_ = H_ / KVH_;            // 4
constexpr int F_ = E_ + 2 * KVH_ * D_;     // 6144
constexpr int M_ = B_ * S_;                // 4096 rows of x

// ---------- fp32 -> bf16 convert (8 elems/thread) ----------
__global__ void f2bf_k(const float* __restrict__ in, bf16* __restrict__ out, int n8) {
  int i = blockIdx.x * 256 + threadIdx.x;
  if (i >= n8) return;
  const float4* p = (const float4*)(in + (size_t)i * 8);
  float4 a = p[0], b = p[1];
  bf16x8 o;
  o[0] = (bf16)a.x; o[1] = (bf16)a.y; o[2] = (bf16)a.z; o[3] = (bf16)a.w;
  o[4] = (bf16)b.x; o[5] = (bf16)b.y; o[6] = (bf16)b.z; o[7] = (bf16)b.w;
  *(bf16x8*)(out + (size_t)i * 8) = o;
}

// ---------- RoPE cos/sin table ----------
__global__ void rope_table_k(float2* __restrict__ tab) {
  int i = blockIdx.x * 256 + threadIdx.x;   // S_*64 = 131072
  int s = i >> 6, f = i & 63;
  float inv = powf(10000.0f, -2.0f * (float)f / 128.0f);
  float ang = (float)s * inv;
  tab[i] = make_float2(cosf(ang), sinf(ang));
}

// ============ 256x256 2-PHASE bf16 GEMM ============
// C[M][N] = A[M][K]*B[N][K]^T. 512 thr = 8 waves (2M x 4N); per-wave 128x64
// (acc[8][4]); BK=64. r7 cycle model: MFMA floor 2480 cyc/K-tile, measured
// 6100 -> ~700 cyc of per-phase serial overhead (barriers+lgkm+read issue) x 4
// phases. Fix: 2 fat phases/K-tile (32 MFMA each) halves the overhead events.
// A dbuf staged t+1 (1-phase slack); B TRI-buffered staged t+2 so the boundary
// wait stays counted vmcnt(4), never 0 mid-loop (T4). LDS = 2x32K + 3x32K =
// 160KB (full pool). Swizzle via pre-swz global source (rule 21) + swz ds_read;
// raw barriers + clobber-free waits (r4 lesson); setprio around MFMA.
template <typename OutT>
__global__ __launch_bounds__(512, 2)
void gemm256(const bf16* __restrict__ A, const bf16* __restrict__ B,
             OutT* __restrict__ C, int M, int N, int K) {
  __shared__ bf16 As[2][16384];   // [256 rows][64 el], 128B rows, 32KB each
  __shared__ bf16 Bs[3][16384];
  const int tid = threadIdx.x;
  const int wid = tid >> 6, lane = tid & 63;
  const int l15 = lane & 15, g = lane >> 4;
  const int wr = wid >> 2, wc = wid & 3;
  const int bm = blockIdx.x, bn = blockIdx.y;
  const bf16* Ab = A + (size_t)bm * 256 * K;
  const bf16* Bb = B + (size_t)bn * 256 * K;
  const int nT = K >> 6;
  const int swzr = (l15 & 7) << 4;  // read-side byte swizzle for row = *+l15

  f32x4 acc[8][4];
#pragma unroll
  for (int m = 0; m < 8; ++m)
#pragma unroll
    for (int n = 0; n < 4; ++n) acc[m][n] = (f32x4){0.f, 0.f, 0.f, 0.f};

  // stage a FULL 256x64 tile (32KB, 4 loads/thread); linear gload_lds dest,
  // inverse-swizzled global source column.
  auto stgA = [&](int t) {
#pragma unroll
    for (int i = 0; i < 4; ++i) {
      int lb = i * 8192 + wid * 1024 + lane * 16;
      int row = lb >> 7;
      int colb = (lb & 127) ^ ((row & 7) << 4);
      gload16(Ab + (size_t)row * K + t * 64 + (colb >> 1),
              &As[t & 1][(i * 8192 + wid * 1024) >> 1]);
    }
  };
  auto stgB = [&](int t) {
    bf16* dst = &Bs[t % 3][0];
#pragma unroll
    for (int i = 0; i < 4; ++i) {
      int lb = i * 8192 + wid * 1024 + lane * 16;
      int row = lb >> 7;
      int colb = (lb & 127) ^ ((row & 7) << 4);
      gload16(Bb + (size_t)row * K + t * 64 + (colb >> 1),
              dst + ((i * 8192 + wid * 1024) >> 1));
    }
  };

  // ---- prologue: B0, A0 staged + B1 issued; wait B0/A0, keep B1 in flight
  stgB(0); stgA(0);
  if (nT > 1) { stgB(1); asm volatile("s_waitcnt vmcnt(4)"); }
  else        { asm volatile("s_waitcnt vmcnt(0)"); }
  __builtin_amdgcn_sched_barrier(0);
  __builtin_amdgcn_s_barrier();

  bf16x8 af[8][2], blo[2][2], bhi[2][2];
  for (int t = 0; t < nT; ++t) {
    const bf16* Asc = &As[t & 1][0];
    const bf16* Bsc = &Bs[t % 3][0];
    // -------- P1: ALL A-frags (16 reads) + B-lo (4); stage A(t+1) --------
#pragma unroll
    for (int m = 0; m < 8; ++m) {
      int arow = wr * 128 + m * 16 + l15;
#pragma unroll
      for (int ks = 0; ks < 2; ++ks)
        af[m][ks] = *(const bf16x8*)&Asc[(arow << 6) + (((ks * 64 + g * 16) ^ swzr) >> 1)];
    }
#pragma unroll
    for (int n = 0; n < 2; ++n) {
      int brow = wc * 64 + n * 16 + l15;
#pragma unroll
      for (int ks = 0; ks < 2; ++ks)
        blo[n][ks] = *(const bf16x8*)&Bsc[(brow << 6) + (((ks * 64 + g * 16) ^ swzr) >> 1)];
    }
    if (t + 1 < nT) stgA(t + 1);
    __builtin_amdgcn_s_barrier();
    asm volatile("s_waitcnt lgkmcnt(0)");
    __builtin_amdgcn_sched_barrier(0);
    __builtin_amdgcn_s_setprio(1);
#pragma unroll
    for (int ks = 0; ks < 2; ++ks)
#pragma unroll
      for (int m = 0; m < 8; ++m)
#pragma unroll
        for (int n = 0; n < 2; ++n)
          acc[m][n] = __builtin_amdgcn_mfma_f32_16x16x32_bf16(af[m][ks], blo[n][ks], acc[m][n], 0, 0, 0);
    __builtin_amdgcn_s_setprio(0);
    __builtin_amdgcn_s_barrier();
    // -------- P2: B-hi (4 reads); stage B(t+2); counted boundary vmcnt --------
#pragma unroll
    for (int n = 0; n < 2; ++n) {
      int brow = wc * 64 + 32 + n * 16 + l15;
#pragma unroll
      for (int ks = 0; ks < 2; ++ks)
        bhi[n][ks] = *(const bf16x8*)&Bsc[(brow << 6) + (((ks * 64 + g * 16) ^ swzr) >> 1)];
    }
    if (t + 2 < nT) stgB(t + 2);
    __builtin_amdgcn_s_barrier();
    asm volatile("s_waitcnt lgkmcnt(0)");
    __builtin_amdgcn_sched_barrier(0);
    __builtin_amdgcn_s_setprio(1);
#pragma unroll
    for (int ks = 0; ks < 2; ++ks)
#pragma unroll
      for (int m = 0; m < 8; ++m)
#pragma unroll
        for (int n = 0; n < 2; ++n)
          acc[m][2 + n] = __builtin_amdgcn_mfma_f32_16x16x32_bf16(af[m][ks], bhi[n][ks], acc[m][2 + n], 0, 0, 0);
    __builtin_amdgcn_s_setprio(0);
    // A(t+1) + B(t+1) must be resident before next P1; keep B(t+2) (newest 4)
    // in flight across the barrier.
    if (t + 2 < nT)      { asm volatile("s_waitcnt vmcnt(4)"); }
    else if (t + 1 < nT) { asm volatile("s_waitcnt vmcnt(0)"); }
    __builtin_amdgcn_sched_barrier(0);
    __builtin_amdgcn_s_barrier();
  }

  // epilogue: C/D layout col=lane&15, row=(lane>>4)*4+r  [measured m89]
#pragma unroll
  for (int m = 0; m < 8; ++m) {
    int row0 = bm * 256 + wr * 128 + m * 16 + g * 4;
#pragma unroll
    for (int ni = 0; ni < 4; ++ni) {
      int col = bn * 256 + wc * 64 + ni * 16 + l15;
      f32x4 v = acc[m][ni];
#pragma unroll
      for (int r = 0; r < 4; ++r)
        C[(size_t)(row0 + r) * N + col] = (OutT)v[r];
    }
  }
}

// ---------- RoPE on Q: qkv[M][F] -> q[B][S][H][D] (interleaved pairs) ----------
__global__ void rope_q_k(const bf16* __restrict__ qkv, const float2* __restrict__ tab,
                         bf16* __restrict__ qout) {
  int idx = blockIdx.x * 256 + threadIdx.x;  // B*S*H*16 = 2097152
  int c = idx & 15;
  int h = (idx >> 4) & 31;
  int s = (idx >> 9) & 2047;
  int b = idx >> 20;
  int d0 = c * 8;
  int kvh = h >> 2, j = h & 3;
  const bf16* src = qkv + (size_t)(b * 2048 + s) * F_ + kvh * (QPK_ + 2) * D_ + j * D_ + d0;
  bf16x8 v = *(const bf16x8*)src;
  const float2* tb = tab + s * 64 + (d0 >> 1);
  bf16x8 o;
#pragma unroll
  for (int p = 0; p < 4; ++p) {
    float x0 = (float)v[2 * p], x1 = (float)v[2 * p + 1];
    float2 cs = tb[p];
    o[2 * p]     = (bf16)(x0 * cs.x - x1 * cs.y);
    o[2 * p + 1] = (bf16)(x0 * cs.y + x1 * cs.x);
  }
  *(bf16x8*)(qout + (((size_t)b * 2048 + s) * 32 + h) * 128 + d0) = o;
}

// ---------- RoPE on K: qkv -> k[B][KVH][S][D] ----------
__global__ void rope_k_k(const bf16* __restrict__ qkv, const float2* __restrict__ tab,
                         bf16* __restrict__ kout) {
  int idx = blockIdx.x * 256 + threadIdx.x;  // B*S*KVH*16 = 524288
  int c = idx & 15;
  int kvh = (idx >> 4) & 7;
  int s = (idx >> 7) & 2047;
  int b = idx >> 18;
  int d0 = c * 8;
  const bf16* src = qkv + (size_t)(b * 2048 + s) * F_ + kvh * (QPK_ + 2) * D_ + QPK_ * D_ + d0;
  bf16x8 v = *(const bf16x8*)src;
  const float2* tb = tab + s * 64 + (d0 >> 1);
  bf16x8 o;
#pragma unroll
  for (int p = 0; p < 4; ++p) {
    float x0 = (float)v[2 * p], x1 = (float)v[2 * p + 1];
    float2 cs = tb[p];
    o[2 * p]     = (bf16)(x0 * cs.x - x1 * cs.y);
    o[2 * p + 1] = (bf16)(x0 * cs.y + x1 * cs.x);
  }
  *(bf16x8*)(kout + ((size_t)(b * 8 + kvh) * 2048 + s) * 128 + d0) = o;
}

// ---------- V transpose: qkv -> vt[B][KVH][D][S] (LDS tiled 64s x 32d) ----------
__global__ void vtrans_k(const bf16* __restrict__ qkv, bf16* __restrict__ vt) {
  int bidx = blockIdx.x;  // B*KVH*4*32 = 2048
  int st = bidx & 31;
  int dt = (bidx >> 5) & 3;
  int kvh = (bidx >> 7) & 7;
  int b = bidx >> 10;
  __shared__ bf16 tile[64][40];
  int t = threadIdx.x;
  {
    int sl = t >> 2, d0 = (t & 3) * 8;
    bf16x8 v = *(const bf16x8*)(qkv + (size_t)(b * 2048 + st * 64 + sl) * F_ +
                                kvh * (QPK_ + 2) * D_ + (QPK_ + 1) * D_ + dt * 32 + d0);
#pragma unroll
    for (int i = 0; i < 8; ++i) tile[sl][d0 + i] = v[i];
  }
  __syncthreads();
  {
    int dl = t >> 3, s0 = (t & 7) * 8;
    bf16x8 o;
#pragma unroll
    for (int i = 0; i < 8; ++i) o[i] = tile[s0 + i][dl];
    *(bf16x8*)(vt + ((size_t)(b * 8 + kvh) * 128 + dt * 32 + dl) * 2048 + st * 64 + s0) = o;
  }
}

// ---------- causal GQA flash attention (r5 structure, unchanged) ----------
__global__ __launch_bounds__(512, 2)
void attn_k(const bf16* __restrict__ q, const bf16* __restrict__ k,
            const bf16* __restrict__ vt, bf16* __restrict__ ctx) {
  int bid = blockIdx.x;
  bid = (bid & 7) * 64 + (bid >> 3);   // XCD chunk: each XCD gets 2 (b,kvh) KV sets
  int qp = bid & 7;
  int h = (bid >> 3) & 31;
  int b = bid >> 8;
  int kvh = h >> 2;
  int tid = threadIdx.x, w = tid >> 6, lane = tid & 63;
  int l15 = lane & 15, g = lane >> 4;

  __shared__ bf16 Ks[3][64 * 128];
  __shared__ bf16 Vs[3][128 * 64];
  __shared__ bf16 Plds[8][16 * 80];

  bf16* Pw = &Plds[w][0];
  const float C2 = 0.08838834764831845f * 1.4426950408889634f;
  const float NEG = -3.0e38f;

  const bf16* kb_base = k + (size_t)(b * 8 + kvh) * 2048 * 128;
  const bf16* vt_base = vt + (size_t)(b * 8 + kvh) * 128 * 2048;

  auto stage = [&](int kv0, int buf) {
#pragma unroll
    for (int i = 0; i < 2; ++i) {
      int lt = i * 8192 + tid * 16;
      int row = lt >> 8;
      int ch = (lt >> 4) & 15;
      int srcel = (ch ^ (row & 7)) << 3;
      gload16(kb_base + (size_t)(kv0 + row) * 128 + srcel,
              &Ks[buf][(i * 8192 + w * 1024) >> 1]);
    }
#pragma unroll
    for (int i = 0; i < 2; ++i) {
      int lt = i * 8192 + tid * 16;
      int row = lt >> 7;
      int ch = (lt >> 4) & 7;
      int srcel = (ch ^ (row & 7)) << 3;
      gload16(vt_base + (size_t)row * 2048 + kv0 + srcel,
              &Vs[buf][(i * 8192 + w * 1024) >> 1]);
    }
  };

  const int kxor = (l15 & 7) << 4;

  for (int pass = 0; pass < 2; ++pass) {
    int qt = pass ? (15 - qp) : qp;
    int qrow0 = qt * 128 + w * 16;

    bf16x8 aq[4];
#pragma unroll
    for (int ks = 0; ks < 4; ++ks)
      aq[ks] = *(const bf16x8*)(q + (((size_t)b * 2048 + qrow0 + l15) * 32 + h) * 128 + ks * 32 + g * 8);

    f32x4 acco[8];
#pragma unroll
    for (int n = 0; n < 8; ++n) acco[n] = (f32x4){0.f, 0.f, 0.f, 0.f};
    float m_r[4] = {NEG, NEG, NEG, NEG};
    float l_r[4] = {0.f, 0.f, 0.f, 0.f};

    const int nk = 2 * qt + 2;
    stage(0, 0);
    stage(64, 1);
    asm volatile("s_waitcnt vmcnt(4)");
    __builtin_amdgcn_sched_barrier(0);
    __builtin_amdgcn_s_barrier();

    for (int kt = 0; kt < nk; ++kt) {
      int kv0 = kt * 64;
      int cur = kt % 3;
      if (kt + 2 < nk) stage(kv0 + 128, (kt + 2) % 3);

      if (kv0 <= qrow0 + 15) {
        f32x4 s[4];
#pragma unroll
        for (int n = 0; n < 4; ++n) s[n] = (f32x4){0.f, 0.f, 0.f, 0.f};
#pragma unroll
        for (int ks = 0; ks < 4; ++ks) {
          int off = ((ks * 64 + g * 16) ^ kxor) >> 1;
#pragma unroll
          for (int n = 0; n < 4; ++n) {
            bf16x8 kb = *(const bf16x8*)&Ks[cur][(n * 16 + l15) * 128 + off];
            s[n] = __builtin_amdgcn_mfma_f32_16x16x32_bf16(aq[ks], kb, s[n], 0, 0, 0);
          }
        }
        if (kv0 + 63 > qrow0) {
#pragma unroll
          for (int n = 0; n < 4; ++n)
#pragma unroll
            for (int r = 0; r < 4; ++r) {
              int qg = qrow0 + g * 4 + r;
              int kg = kv0 + n * 16 + l15;
              if (kg > qg) s[n][r] = NEG;
            }
        }
        float fac[4];
#pragma unroll
        for (int r = 0; r < 4; ++r) {
          float mx = fmaxf(fmaxf(s[0][r], s[1][r]), fmaxf(s[2][r], s[3][r]));
#pragma unroll
          for (int off = 1; off < 16; off <<= 1) mx = fmaxf(mx, __shfl_xor(mx, off));
          float mn = fmaxf(m_r[r], mx);
          fac[r] = exp2f((m_r[r] - mn) * C2);
          m_r[r] = mn;
        }
        float psum[4] = {0.f, 0.f, 0.f, 0.f};
#pragma unroll
        for (int n = 0; n < 4; ++n)
#pragma unroll
          for (int r = 0; r < 4; ++r) {
            float p = exp2f((s[n][r] - m_r[r]) * C2);
            psum[r] += p;
            Pw[(g * 4 + r) * 80 + n * 16 + l15] = (bf16)p;
          }
#pragma unroll
        for (int r = 0; r < 4; ++r) {
          float ps = psum[r];
#pragma unroll
          for (int off = 1; off < 16; off <<= 1) ps += __shfl_xor(ps, off);
          l_r[r] = l_r[r] * fac[r] + ps;
        }
#pragma unroll
        for (int n = 0; n < 8; ++n)
#pragma unroll
          for (int r = 0; r < 4; ++r) acco[n][r] *= fac[r];
        __builtin_amdgcn_sched_barrier(0);
        asm volatile("s_waitcnt lgkmcnt(0)");
        __builtin_amdgcn_sched_barrier(0);
#pragma unroll
        for (int ks = 0; ks < 2; ++ks) {
          bf16x8 pa = *(const bf16x8*)&Pw[l15 * 80 + ks * 32 + g * 8];
          int off = ((ks * 64 + g * 16) ^ kxor) >> 1;
#pragma unroll
          for (int n = 0; n < 8; ++n) {
            bf16x8 vb = *(const bf16x8*)&Vs[cur][(n * 16 + l15) * 64 + off];
            acco[n] = __builtin_amdgcn_mfma_f32_16x16x32_bf16(pa, vb, acco[n], 0, 0, 0);
          }
        }
      }

      if (kt + 1 < nk) {
        if (kt + 2 < nk) { asm volatile("s_waitcnt vmcnt(4)"); }
        else             { asm volatile("s_waitcnt vmcnt(0)"); }
        __builtin_amdgcn_sched_barrier(0);
      }
      __builtin_amdgcn_s_barrier();
    }

#pragma unroll
    for (int r = 0; r < 4; ++r) {
      float inv = 1.0f / l_r[r];
      int qg = qrow0 + g * 4 + r;
#pragma unroll
      for (int n = 0; n < 8; ++n)
        ctx[(((size_t)b * 2048 + qg) * 32 + h) * 128 + n * 16 + l15] = (bf16)(acco[n][r] * inv);
    }
  }
}

// ---------- launcher ----------
extern "C" void kernel_launch(void* const* d_in, const int* in_sizes, int n_in,
                              void* d_out, int out_size, void* d_ws, size_t ws_size,
                              hipStream_t stream) {
  const float* x = (const float*)d_in[0];
  const float* wqkv = (const float*)d_in[1];
  const float* wo = (const float*)d_in[2];
  float* out = (float*)d_out;
  char* ws = (char*)d_ws;

  // workspace layout (bytes); total = 185,597,952
  bf16* xbf    = (bf16*)(ws + 0);            // 33,554,432  (reused as ctx later)
  bf16* wqkvbf = (bf16*)(ws + 33554432);     // 50,331,648
  bf16* qkvbf  = (bf16*)(ws + 83886080);     // 50,331,648  (reused as wo_bf later)
  bf16* qbuf   = (bf16*)(ws + 134217728);    // 33,554,432
  bf16* kbuf   = (bf16*)(ws + 167772160);    // 8,388,608
  bf16* vtbuf  = (bf16*)(ws + 176160768);    // 8,388,608
  float2* tab  = (float2*)(ws + 184549376);  // 1,048,576

  // 1. converts + rope table
  f2bf_k<<<8192, 256, 0, stream>>>(x, xbf, M_ * E_ / 8);
  f2bf_k<<<12288, 256, 0, stream>>>(wqkv, wqkvbf, F_ * E_ / 8);
  rope_table_k<<<512, 256, 0, stream>>>(tab);

  // 2. QKV projection: qkv[M][F] = x[M][E] * wqkv[F][E]^T
  gemm256<bf16><<<dim3(M_ / 256, F_ / 256), 512, 0, stream>>>(xbf, wqkvbf, qkvbf, M_, F_, E_);

  // 3. RoPE + layout shuffles
  rope_q_k<<<8192, 256, 0, stream>>>(qkvbf, tab, qbuf);
  rope_k_k<<<2048, 256, 0, stream>>>(qkvbf, tab, kbuf);
  vtrans_k<<<2048, 256, 0, stream>>>(qkvbf, vtbuf);

  // 4. convert wo into the (now dead) qkv region
  bf16* wobf = qkvbf;
  f2bf_k<<<8192, 256, 0, stream>>>(wo, wobf, E_ * E_ / 8);

  // 5. attention -> ctx (reuses xbf region, dead after GEMM1)
  bf16* ctx = xbf;
  attn_k<<<512, 512, 0, stream>>>(qbuf, kbuf, vtbuf, ctx);

  // 6. output projection: out[M][E] = ctx[M][E] * wo[E][E]^T  (fp32 out)
  gemm256<float><<<dim3(M_ / 256, E_ / 256), 512, 0, stream>>>(ctx, wobf, out, M_, E_, E_);
}